// Round 7
// baseline (375.679 us; speedup 1.0000x reference)
//
#include <hip/hip_runtime.h>
#include <hip/hip_bf16.h>
#include <stdint.h>

// Problem constants
#define M_DIM 8192   // B*S = 4*2048
#define N_C   4096   // contraction dim (N in reference)
#define K_OUT 4096   // output features (K in reference)
#define NGRP  32
#define NT16  (N_C / 16)   // 256 K-steps of 16

typedef __attribute__((ext_vector_type(8))) short bf16x8;
typedef __attribute__((ext_vector_type(16))) float f32x16;

// fp32 -> bf16, round-to-nearest-even (inputs are finite)
__device__ __forceinline__ unsigned short f2b(float f) {
  unsigned u = __float_as_uint(f);
  return (unsigned short)((u + 0x7fffu + ((u >> 16) & 1u)) >> 16);
}

__device__ __forceinline__ void gload_lds16(const void* g, void* l) {
  __builtin_amdgcn_global_load_lds(
      (const __attribute__((address_space(1))) void*)g,
      (__attribute__((address_space(3))) void*)l,
      16, 0, 0);
}

// ---- x fp32 -> bf16 ----
__global__ void convert_x_kernel(const float* __restrict__ x,
                                 unsigned short* __restrict__ xb) {
  const int total = (M_DIM * N_C) / 8;
  const int stride = gridDim.x * blockDim.x;
  for (int i = blockIdx.x * blockDim.x + threadIdx.x; i < total; i += stride) {
    const float4* p = (const float4*)(x + (size_t)i * 8);
    float4 a = p[0];
    float4 b = p[1];
    union { unsigned short u[8]; uint4 v; } o;
    o.u[0] = f2b(a.x); o.u[1] = f2b(a.y); o.u[2] = f2b(a.z); o.u[3] = f2b(a.w);
    o.u[4] = f2b(b.x); o.u[5] = f2b(b.y); o.u[6] = f2b(b.z); o.u[7] = f2b(b.w);
    *(uint4*)(xb + (size_t)i * 8) = o.v;
  }
}

// ---- W dequant -> bf16 [K_OUT][N_C] ----
__global__ void dequant_w_kernel(const int* __restrict__ Wq,
                                 const float* __restrict__ scales,
                                 const float* __restrict__ zeros,
                                 const float* __restrict__ mu1,
                                 const float* __restrict__ mu2,
                                 unsigned short* __restrict__ wb) {
  const int total = (K_OUT * N_C) / 8;
  const int stride = gridDim.x * blockDim.x;
  for (int i = blockIdx.x * blockDim.x + threadIdx.x; i < total; i += stride) {
    const int k  = i >> 9;
    const int nc = (i & 511) << 3;
    const int g  = nc >> 7;
    const float s = scales[k * NGRP + g];
    const float z = zeros[k * NGRP + g];
    const float f  = s * mu2[k];
    const float zf = z * f;
    const int4* q4 = (const int4*)(Wq + (size_t)k * N_C + nc);
    int4 q0 = q4[0], q1 = q4[1];
    const float4* m4 = (const float4*)(mu1 + nc);
    float4 m0 = m4[0], m1 = m4[1];
    union { unsigned short u[8]; uint4 v; } o;
    o.u[0] = f2b(((float)q0.x * f - zf) * m0.x);
    o.u[1] = f2b(((float)q0.y * f - zf) * m0.y);
    o.u[2] = f2b(((float)q0.z * f - zf) * m0.z);
    o.u[3] = f2b(((float)q0.w * f - zf) * m0.w);
    o.u[4] = f2b(((float)q1.x * f - zf) * m1.x);
    o.u[5] = f2b(((float)q1.y * f - zf) * m1.y);
    o.u[6] = f2b(((float)q1.z * f - zf) * m1.z);
    o.u[7] = f2b(((float)q1.w * f - zf) * m1.w);
    *(uint4*)(wb + (size_t)i * 8) = o.v;
  }
}

// ---- Register-pipelined bf16 GEMM: out[m][n] = sum_k Xb[m][k]*Wb[n][k]+bias
// 256x256 tile, 8 waves (2Mx4N, per-wave 128x64), MFMA 32x32x16.
// K-step = 16. LDS: 4 buffers x 16KB (A 8KB [256r x 32B], B 8KB), 64KB total.
// Swizzle: 16B slot s' = s ^ (row&1) (derived conflict-free: 8 accesses/bank,
// distinct addresses). Staging: linear LDS dst + inverse-swizzled global src.
// Register pipeline: per iter t: {vmcnt(2)+barrier; 6 ds_reads of frags(t+1)
// into NEXT set; stage(t+3); 8 MFMA on CUR set (register-only, NO lgkm wait)}
// -> LDS service of t+1 overlaps MFMA of t within each wave.
// Ledger: stage(t) = 2 gload_lds. At top of iter t, outstanding = stage(t+1),
// stage(t+2) (4 loads) -> vmcnt(2) proves stage(t+1); barrier makes it CU-wide.
// Buffer safety: stage(t+3) (issued in body t, after the clobbered barrier)
// overwrites buf[(t-1)&3]; its reads (frags(t-1), issued body t-2) were
// register-consumed by MFMAs in body t-1 (lgkm-drained) before every wave
// passed barrier(t). Reads of frags(t+1) cannot hoist above the vmcnt+barrier
// asm (memory ops vs clobber); MFMAs may float (register-only) - harmless.
__global__ __launch_bounds__(512, 2) void gemm_bf16_kernel(
    const unsigned short* __restrict__ Xb,   // [M_DIM][N_C] bf16
    const unsigned short* __restrict__ Wb,   // [K_OUT][N_C] bf16
    const float* __restrict__ bias,          // [K_OUT]
    float* __restrict__ out) {               // [M_DIM][K_OUT]
  __shared__ unsigned short smem[32768];     // 64 KiB: 4 bufs x 16 KiB

  // XCD-aware bijective swizzle: 512 blocks, 8 XCDs, 64 per XCD
  const int bid = blockIdx.x;
  const int swz = (bid & 7) * 64 + (bid >> 3);
  const int n0 = (swz & 15) * 256;
  const int m0 = (swz >> 4) * 256;

  const int tid = threadIdx.x;
  const int w   = tid >> 6;
  const int l   = tid & 63;
  const int wr  = w >> 2;     // 0..1 -> 128 rows
  const int wc  = w & 3;      // 0..3 -> 64 cols

  const char* Xc = (const char*)Xb;
  const char* Wc = (const char*)Wb;
  char* ldsc = (char*)smem;

  // ---- staging: thread covers row rS, 16B half sLog of the 32B k-slice ----
  const int rS   = w * 32 + (l >> 1);              // 0..255
  const int sLog = (l & 1) ^ ((l >> 1) & 1);       // inverse swizzle (involution)
  const char* srcA0 = Xc + (size_t)(m0 + rS) * 8192 + sLog * 16;
  const char* srcB0 = Wc + (size_t)(n0 + rS) * 8192 + sLog * 16;
  const int dstA = w * 1024 + l * 16;              // linear, A region [0,8192)
  const int dstB = 8192 + dstA;                    // B region

  // ---- swizzled ds_read byte offsets (within one 16KB buffer) ----
  // frag row r: A_i: wr*128+i*32+(l&31); B_j: wc*64+j*32+(l&31); r&1 == l&1.
  const int sbit = ((l >> 5) ^ (l & 1));
  const int offA0 = (wr * 128 + (l & 31)) * 32 + sbit * 16;
  const int offB0 = 8192 + (wc * 64 + (l & 31)) * 32 + sbit * 16;

  f32x16 acc[4][2] = {};
  bf16x8 S0a0, S0a1, S0a2, S0a3, S0b0, S0b1;   // frag set 0
  bf16x8 S1a0, S1a1, S1a2, S1a3, S1b0, S1b1;   // frag set 1

#define STAGE(tt) { char* nb = ldsc + ((tt) & 3) * 16384;                    \
    const size_t ko = (size_t)(tt) * 32;                                     \
    gload_lds16(srcA0 + ko, nb + dstA);                                      \
    gload_lds16(srcB0 + ko, nb + dstB); }

#define MFMA32(aa, bb, cc) __builtin_amdgcn_mfma_f32_32x32x16_bf16(aa, bb, cc, 0, 0, 0)

#define ITER(VMSTR, tt, DOSTAGE, Ca0,Ca1,Ca2,Ca3,Cb0,Cb1, Na0,Na1,Na2,Na3,Nb0,Nb1) \
  { asm volatile("s_waitcnt vmcnt(" VMSTR ")\n\ts_barrier" ::: "memory");    \
    const char* bp = ldsc + (((tt) + 1) & 3) * 16384;                        \
    Na0 = *(const bf16x8*)(bp + offA0);                                      \
    Na1 = *(const bf16x8*)(bp + offA0 + 1024);                               \
    Na2 = *(const bf16x8*)(bp + offA0 + 2048);                               \
    Na3 = *(const bf16x8*)(bp + offA0 + 3072);                               \
    Nb0 = *(const bf16x8*)(bp + offB0);                                      \
    Nb1 = *(const bf16x8*)(bp + offB0 + 1024);                               \
    if (DOSTAGE) STAGE((tt) + 3)                                             \
    __builtin_amdgcn_s_setprio(1);                                           \
    acc[0][0] = MFMA32(Ca0, Cb0, acc[0][0]);                                 \
    acc[1][0] = MFMA32(Ca1, Cb0, acc[1][0]);                                 \
    acc[2][0] = MFMA32(Ca2, Cb0, acc[2][0]);                                 \
    acc[3][0] = MFMA32(Ca3, Cb0, acc[3][0]);                                 \
    acc[0][1] = MFMA32(Ca0, Cb1, acc[0][1]);                                 \
    acc[1][1] = MFMA32(Ca1, Cb1, acc[1][1]);                                 \
    acc[2][1] = MFMA32(Ca2, Cb1, acc[2][1]);                                 \
    acc[3][1] = MFMA32(Ca3, Cb1, acc[3][1]);                                 \
    __builtin_amdgcn_s_setprio(0); }

  // Prologue: stage 0,1,2 (6 loads); vmcnt(4) proves stage(0); read frags(0).
  STAGE(0)
  STAGE(1)
  STAGE(2)
  asm volatile("s_waitcnt vmcnt(4)\n\ts_barrier" ::: "memory");
  {
    const char* bp = ldsc;   // buf 0
    S0a0 = *(const bf16x8*)(bp + offA0);
    S0a1 = *(const bf16x8*)(bp + offA0 + 1024);
    S0a2 = *(const bf16x8*)(bp + offA0 + 2048);
    S0a3 = *(const bf16x8*)(bp + offA0 + 3072);
    S0b0 = *(const bf16x8*)(bp + offB0);
    S0b1 = *(const bf16x8*)(bp + offB0 + 1024);
  }

  // Main loop: t = 0..251 (even t uses set0 as CUR). Stages 3..254.
#pragma unroll 1
  for (int t = 0; t < NT16 - 4; t += 2) {
    ITER("2", t,     1, S0a0,S0a1,S0a2,S0a3,S0b0,S0b1, S1a0,S1a1,S1a2,S1a3,S1b0,S1b1)
    ITER("2", t + 1, 1, S1a0,S1a1,S1a2,S1a3,S1b0,S1b1, S0a0,S0a1,S0a2,S0a3,S0b0,S0b1)
  }
  // t=252: stages 255 (last). t=253,254: no staging. t=254 drains vmcnt.
  ITER("2", NT16 - 4, 1, S0a0,S0a1,S0a2,S0a3,S0b0,S0b1, S1a0,S1a1,S1a2,S1a3,S1b0,S1b1)
  ITER("2", NT16 - 3, 0, S1a0,S1a1,S1a2,S1a3,S1b0,S1b1, S0a0,S0a1,S0a2,S0a3,S0b0,S0b1)
  ITER("0", NT16 - 2, 0, S0a0,S0a1,S0a2,S0a3,S0b0,S0b1, S1a0,S1a1,S1a2,S1a3,S1b0,S1b1)
  // Final K-step: MFMA on set1 (frags(255)), no reads/stage/barrier needed.
  __builtin_amdgcn_s_setprio(1);
  acc[0][0] = MFMA32(S1a0, S1b0, acc[0][0]);
  acc[1][0] = MFMA32(S1a1, S1b0, acc[1][0]);
  acc[2][0] = MFMA32(S1a2, S1b0, acc[2][0]);
  acc[3][0] = MFMA32(S1a3, S1b0, acc[3][0]);
  acc[0][1] = MFMA32(S1a0, S1b1, acc[0][1]);
  acc[1][1] = MFMA32(S1a1, S1b1, acc[1][1]);
  acc[2][1] = MFMA32(S1a2, S1b1, acc[2][1]);
  acc[3][1] = MFMA32(S1a3, S1b1, acc[3][1]);
  __builtin_amdgcn_s_setprio(0);

#undef ITER
#undef MFMA32
#undef STAGE

  // Epilogue: 32x32 C/D layout (m74/m101 verified):
  // col = lane&31, row = (reg&3) + 8*(reg>>2) + 4*(lane>>5).
#pragma unroll
  for (int j = 0; j < 2; ++j) {
    const int col = n0 + wc * 64 + j * 32 + (l & 31);
    const float bv = bias[col];
#pragma unroll
    for (int i = 0; i < 4; ++i) {
      const int rbase = m0 + wr * 128 + i * 32 + 4 * (l >> 5);
#pragma unroll
      for (int rr = 0; rr < 16; ++rr) {
        const int row = rbase + (rr & 3) + 8 * (rr >> 2);
        out[(size_t)row * K_OUT + col] = acc[i][j][rr] + bv;
      }
    }
  }
}

extern "C" void kernel_launch(void* const* d_in, const int* in_sizes, int n_in,
                              void* d_out, int out_size, void* d_ws, size_t ws_size,
                              hipStream_t stream) {
  const float* x      = (const float*)d_in[0];
  const int*   Wq     = (const int*)d_in[1];
  const float* scales = (const float*)d_in[2];
  const float* zeros  = (const float*)d_in[3];
  const float* mu1    = (const float*)d_in[4];
  const float* mu2    = (const float*)d_in[5];
  const float* bias   = (const float*)d_in[6];
  float* out = (float*)d_out;

  unsigned short* xb = (unsigned short*)d_ws;
  unsigned short* wb = xb + (size_t)M_DIM * N_C;

  convert_x_kernel<<<2048, 256, 0, stream>>>(x, xb);
  dequant_w_kernel<<<2048, 256, 0, stream>>>(Wq, scales, zeros, mu1, mu2, wb);

  dim3 grid((M_DIM / 256) * (K_OUT / 256));   // 512 blocks
  gemm_bf16_kernel<<<grid, 512, 0, stream>>>(xb, wb, bias, out);
}